// Round 9
// baseline (205.182 us; speedup 1.0000x reference)
//
#include <hip/hip_runtime.h>

#define T_LEN 512
#define NHID 16
#define NEMB 10
#define VOCAB1 50001
#define IROW 521   // idx row len (ints): covers t+8+3 = 519; 521%32=9 -> rows 9 banks apart

typedef float v2f __attribute__((ext_vector_type(2)));

// ---------------------------------------------------------------------------
// Kernel 1: xproj table, layout [v][16][4] f32: float4 at (v*16+j) =
//   {i,f,g,o} pre-activations for unit j = bih+bhh + emb[v]·Wih rows. (R5)
// ---------------------------------------------------------------------------
__global__ __launch_bounds__(256) void build_table(
    const float* __restrict__ emb, const float* __restrict__ Wih,
    const float* __restrict__ bih, const float* __restrict__ bhh,
    float* __restrict__ tbl)
{
    const int tid = blockIdx.x * 256 + threadIdx.x;
    if (tid >= VOCAB1 * 16) return;
    const int v = tid >> 4, j = tid & 15;
    float e[NEMB];
    #pragma unroll
    for (int i = 0; i < NEMB; ++i) e[i] = emb[v * NEMB + i];
    float o[4];
    #pragma unroll
    for (int q = 0; q < 4; ++q) {
        const int r = q * 16 + j;
        float a = bih[r] + bhh[r];
        #pragma unroll
        for (int i = 0; i < NEMB; ++i) a += e[i] * Wih[r * NEMB + i];
        o[q] = a;
    }
    ((float4*)tbl)[tid] = make_float4(o[0], o[1], o[2], o[3]);
}

// ROW_ROR:r within 16-lane DPP row: D[l] = S[(l-r)&15]  (verified on HW in R8)
#define DPP_ROR(dst, src_i, r)                                                   \
    dst = __builtin_bit_cast(float, __builtin_amdgcn_update_dpp(                 \
              0, src_i, 0x120 + r, 0xF, 0xF, true))

// ---------------------------------------------------------------------------
// Kernel 2: 32 lanes/batch K-SPLIT -> 2048 waves (2/SIMD) with NO duplicated
// FMA work. Lane (hi,j) owns unit j; accumulates its 4 gate rows over the 8
// h-values reachable via DPP rotations {hi*8 .. hi*8+7} of hsrc
// (hsrc = hi ? ror8(h) : h  -> same rotation immediates for both halves).
// Partial sums exchanged with ds_swizzle xor16 (0x401F); add is commutative
// so both halves produce bit-identical gates -> identical c,h per unit.
// Table loads: R5's 4-deep compile-time-indexed pipeline. Token indices
// register-prefetched one macro-iteration ahead (ds_read off critical path).
// ---------------------------------------------------------------------------
__global__ __launch_bounds__(256) void lstm_ks_kernel(
    const int*   __restrict__ x,
    const float* __restrict__ tbl,
    const float* __restrict__ Whh,
    const float* __restrict__ Wfc,
    const float* __restrict__ bfc,
    float*       __restrict__ out)
{
    __shared__ int idxs[8][IROW];    // [batch][t] token*16, 16.7 KB

    const int tid = threadIdx.x;
    const int j   = tid & 15;        // hidden unit owned
    const int hi  = (tid >> 4) & 1;  // k-half (rotation subset)
    const int lb  = tid >> 5;        // local batch 0..7
    const int batch = blockIdx.x * 8 + lb;

    // stage tokens, pre-scaled to float4-row index (v*16); tail -> 0
    #pragma unroll 1
    for (int b = 0; b < 8; ++b) {
        const int* xr = x + (size_t)(blockIdx.x * 8 + b) * T_LEN;
        for (int t = tid; t < IROW; t += 256)
            idxs[b][t] = (t < T_LEN) ? (xr[t] << 4) : 0;
    }
    __syncthreads();

    // per-lane weights: w[q][s] = Whh[q*16+j][(j - hi*8 - s) & 15]
    float w[4][8];
    #pragma unroll
    for (int q = 0; q < 4; ++q) {
        const int row = (q * 16 + j) * NHID;
        #pragma unroll
        for (int s = 0; s < 8; ++s)
            w[q][s] = Whh[row + ((j - hi * 8 - s) & 15)];
    }

    float h = 0.f, c = 0.f;
    const float NL2E  = -1.44269504088896f;
    const float NL2E2 = -2.88539008177793f;
    const float4* t4 = (const float4*)tbl;

    // 4-deep table pipeline + register idx prefetch (one macro-iter ahead)
    float4 pf[4];
    int iv[4];
    #pragma unroll
    for (int s = 0; s < 4; ++s) {
        pf[s] = t4[idxs[lb][s] + j];
        iv[s] = idxs[lb][4 + s];
    }

    #pragma unroll 1
    for (int t = 0; t < T_LEN; t += 4) {
        // idx for NEXT macro-iter's refills (full iteration of slack)
        int ivn[4];
        #pragma unroll
        for (int u = 0; u < 4; ++u) ivn[u] = idxs[lb][t + 8 + u];

        #pragma unroll
        for (int u = 0; u < 4; ++u) {
            const float4 tb = pf[u];
            pf[u] = t4[iv[u] + j];            // in flight 4 steps (counted vmcnt)

            // rotation source for this half: h (hi=0) or ror8(h) (hi=1)
            const int hvi = __builtin_bit_cast(int, h);
            float h8; DPP_ROR(h8, hvi, 8);
            const float hsrc = hi ? h8 : h;
            const int hsi = __builtin_bit_cast(int, hsrc);

            float hr[8];
            hr[0] = hsrc;
            DPP_ROR(hr[1], hsi, 1);  DPP_ROR(hr[2], hsi, 2);
            DPP_ROR(hr[3], hsi, 3);  DPP_ROR(hr[4], hsi, 4);
            DPP_ROR(hr[5], hsi, 5);  DPP_ROR(hr[6], hsi, 6);
            DPP_ROR(hr[7], hsi, 7);

            // half-dot partials for the 4 gates
            float p0 = 0.f, p1 = 0.f, p2 = 0.f, p3 = 0.f;
            #pragma unroll
            for (int s = 0; s < 8; ++s) {
                p0 = fmaf(hr[s], w[0][s], p0);
                p1 = fmaf(hr[s], w[1][s], p1);
                p2 = fmaf(hr[s], w[2][s], p2);
                p3 = fmaf(hr[s], w[3][s], p3);
            }

            // exchange partials with the other half (lane ^ 16)
            const float q0 = __builtin_bit_cast(float,
                __builtin_amdgcn_ds_swizzle(__builtin_bit_cast(int, p0), 0x401F));
            const float q1 = __builtin_bit_cast(float,
                __builtin_amdgcn_ds_swizzle(__builtin_bit_cast(int, p1), 0x401F));
            const float q2 = __builtin_bit_cast(float,
                __builtin_amdgcn_ds_swizzle(__builtin_bit_cast(int, p2), 0x401F));
            const float q3 = __builtin_bit_cast(float,
                __builtin_amdgcn_ds_swizzle(__builtin_bit_cast(int, p3), 0x401F));

            const float a0 = tb.x + (p0 + q0);
            const float a1 = tb.y + (p1 + q1);
            const float a2 = tb.z + (p2 + q2);
            const float a3 = tb.w + (p3 + q3);

            const float ig = __builtin_amdgcn_rcpf(1.f + __builtin_amdgcn_exp2f(a0 * NL2E));
            const float fg = __builtin_amdgcn_rcpf(1.f + __builtin_amdgcn_exp2f(a1 * NL2E));
            const float gg = 2.f * __builtin_amdgcn_rcpf(1.f + __builtin_amdgcn_exp2f(a2 * NL2E2)) - 1.f;
            const float og = __builtin_amdgcn_rcpf(1.f + __builtin_amdgcn_exp2f(a3 * NL2E));

            c = fg * c + ig * gg;
            const float tc = 2.f * __builtin_amdgcn_rcpf(1.f + __builtin_amdgcn_exp2f(c * NL2E2)) - 1.f;
            h = og * tc;
        }

        #pragma unroll
        for (int u = 0; u < 4; ++u) iv[u] = ivn[u];
    }

    // logit: reduce h*Wfc over the 16-lane row (epilogue only)
    float s = h * Wfc[j];
    s += __shfl_xor(s, 1, 64);
    s += __shfl_xor(s, 2, 64);
    s += __shfl_xor(s, 4, 64);
    s += __shfl_xor(s, 8, 64);
    if ((tid & 31) == 0)
        out[batch] = __builtin_amdgcn_rcpf(1.f + __builtin_amdgcn_exp2f((s + bfc[0]) * NL2E));
}

// ---------------------------------------------------------------------------
// Fallback (ws too small for the 12.8 MB table): on-the-fly fp32 path.
// ---------------------------------------------------------------------------
__global__ __launch_bounds__(256) void lstm_fb_kernel(
    const int*   __restrict__ x,
    const float* __restrict__ emb,
    const float* __restrict__ Wih,
    const float* __restrict__ Whh,
    const float* __restrict__ bih,
    const float* __restrict__ bhh,
    const float* __restrict__ Wfc,
    const float* __restrict__ bfc,
    float*       __restrict__ out)
{
    __shared__ int   idx_lds[T_LEN][17];
    __shared__ float hx[16][20];

    const int tid  = threadIdx.x;
    const int lane = tid & 63;
    const int j    = lane & 15;
    const int lb   = tid >> 4;
    const int batch = blockIdx.x * 16 + lb;

    for (int i = tid; i < 16 * T_LEN; i += 256) {
        const int b = i & 15;
        const int t = i >> 4;
        idx_lds[t][b] = x[(blockIdx.x * 16 + b) * T_LEN + t];
    }

    float wih[4][NEMB], bias[4];
    v2f w[4][8];
    #pragma unroll
    for (int q = 0; q < 4; ++q) {
        const int r = j + 16 * q;
        #pragma unroll
        for (int e = 0; e < NEMB; ++e) wih[q][e] = Wih[r * NEMB + e];
        #pragma unroll
        for (int p = 0; p < 8; ++p)
            w[q][p] = (v2f){Whh[r * NHID + 2 * p], Whh[r * NHID + 2 * p + 1]};
        bias[q] = bih[r] + bhh[r];
    }

    __syncthreads();

    v2f h2[8];
    #pragma unroll
    for (int p = 0; p < 8; ++p) h2[p] = (v2f){0.f, 0.f};
    float c = 0.f;

    const float NL2E  = -1.44269504088896f;
    const float NL2E2 = -2.88539008177793f;
    const float4* hp = (const float4*)&hx[lb][0];

    float2 xa, xb, xc, xd, xe2;
    {
        const float2* er = (const float2*)(emb + (long)idx_lds[0][lb] * NEMB);
        xa = er[0]; xb = er[1]; xc = er[2]; xd = er[3]; xe2 = er[4];
    }
    int idx_n = idx_lds[1][lb];

    #pragma unroll 1
    for (int t = 0; t < T_LEN; ++t) {
        const float xv[NEMB] = {xa.x, xa.y, xb.x, xb.y, xc.x, xc.y,
                                xd.x, xd.y, xe2.x, xe2.y};
        if (t + 1 < T_LEN) {
            const float2* er = (const float2*)(emb + (long)idx_n * NEMB);
            xa = er[0]; xb = er[1]; xc = er[2]; xd = er[3]; xe2 = er[4];
        }
        const int idx_nn = (t + 2 < T_LEN) ? idx_lds[t + 2][lb] : 0;

        float v[4];
        #pragma unroll
        for (int q = 0; q < 4; ++q) {
            float a = bias[q];
            #pragma unroll
            for (int e = 0; e < NEMB; ++e) a += xv[e] * wih[q][e];
            v[q] = a;
        }
        v2f a0 = (v2f){v[0], 0.f}, a1 = (v2f){v[1], 0.f};
        v2f a2 = (v2f){v[2], 0.f}, a3 = (v2f){v[3], 0.f};
        #pragma unroll
        for (int p = 0; p < 8; ++p) {
            a0 += h2[p] * w[0][p];
            a1 += h2[p] * w[1][p];
            a2 += h2[p] * w[2][p];
            a3 += h2[p] * w[3][p];
        }
        const float vi = a0.x + a0.y, vf = a1.x + a1.y;
        const float vg = a2.x + a2.y, vo = a3.x + a3.y;

        const float ig = __builtin_amdgcn_rcpf(1.f + __builtin_amdgcn_exp2f(vi * NL2E));
        const float fg = __builtin_amdgcn_rcpf(1.f + __builtin_amdgcn_exp2f(vf * NL2E));
        const float gg = 2.f * __builtin_amdgcn_rcpf(1.f + __builtin_amdgcn_exp2f(vg * NL2E2)) - 1.f;
        const float og = __builtin_amdgcn_rcpf(1.f + __builtin_amdgcn_exp2f(vo * NL2E));

        c = fg * c + ig * gg;
        const float tc = 2.f * __builtin_amdgcn_rcpf(1.f + __builtin_amdgcn_exp2f(c * NL2E2)) - 1.f;
        const float hv = og * tc;

        hx[lb][j] = hv;
        const float4 b0 = hp[0], b1 = hp[1], b2 = hp[2], b3 = hp[3];
        h2[0] = (v2f){b0.x, b0.y}; h2[1] = (v2f){b0.z, b0.w};
        h2[2] = (v2f){b1.x, b1.y}; h2[3] = (v2f){b1.z, b1.w};
        h2[4] = (v2f){b2.x, b2.y}; h2[5] = (v2f){b2.z, b2.w};
        h2[6] = (v2f){b3.x, b3.y}; h2[7] = (v2f){b3.z, b3.w};

        idx_n = idx_nn;
    }

    if (j == 0) {
        float logit = bfc[0];
        #pragma unroll
        for (int p = 0; p < 8; ++p)
            logit += h2[p].x * Wfc[2 * p] + h2[p].y * Wfc[2 * p + 1];
        out[batch] = __builtin_amdgcn_rcpf(1.f + __builtin_amdgcn_exp2f(logit * NL2E));
    }
}

extern "C" void kernel_launch(void* const* d_in, const int* in_sizes, int n_in,
                              void* d_out, int out_size, void* d_ws, size_t ws_size,
                              hipStream_t stream) {
    const int*   x   = (const int*)  d_in[0];
    const float* emb = (const float*)d_in[1];
    const float* Wih = (const float*)d_in[2];
    const float* Whh = (const float*)d_in[3];
    const float* bih = (const float*)d_in[4];
    const float* bhh = (const float*)d_in[5];
    const float* Wfc = (const float*)d_in[6];
    const float* bfc = (const float*)d_in[7];
    float* outp = (float*)d_out;

    const int B = in_sizes[0] / T_LEN;                               // 4096
    const size_t TABLE_BYTES = (size_t)VOCAB1 * 64 * sizeof(float);  // 12.8 MB

    if (ws_size >= TABLE_BYTES) {
        float* tbl = (float*)d_ws;
        build_table<<<(VOCAB1 * 16 + 255) / 256, 256, 0, stream>>>(emb, Wih, bih, bhh, tbl);
        lstm_ks_kernel<<<B / 8, 256, 0, stream>>>(x, tbl, Whh, Wfc, bfc, outp);
    } else {
        lstm_fb_kernel<<<B / 16, 256, 0, stream>>>(x, emb, Wih, Whh, bih, bhh, Wfc, bfc, outp);
    }
}

// Round 10
// 163.981 us; speedup vs baseline: 1.2513x; 1.2513x over previous
//
#include <hip/hip_runtime.h>

#define T_LEN 512
#define NHID 16
#define NEMB 10
#define VOCAB1 50001
#define IROW 521   // idx row len (ints): max ref t+11 = 519; 16 rows of 521 ints

typedef float v2f __attribute__((ext_vector_type(2)));

// ---------------------------------------------------------------------------
// Kernel 1: xproj table, layout [v][16][4] f32: float4 at (v*16+j) =
//   {i,f,g,o} pre-activations for unit j = bih+bhh + emb[v]·Wih rows. (R5)
// ---------------------------------------------------------------------------
__global__ __launch_bounds__(256) void build_table(
    const float* __restrict__ emb, const float* __restrict__ Wih,
    const float* __restrict__ bih, const float* __restrict__ bhh,
    float* __restrict__ tbl)
{
    const int tid = blockIdx.x * 256 + threadIdx.x;
    if (tid >= VOCAB1 * 16) return;
    const int v = tid >> 4, j = tid & 15;
    float e[NEMB];
    #pragma unroll
    for (int i = 0; i < NEMB; ++i) e[i] = emb[v * NEMB + i];
    float o[4];
    #pragma unroll
    for (int q = 0; q < 4; ++q) {
        const int r = q * 16 + j;
        float a = bih[r] + bhh[r];
        #pragma unroll
        for (int i = 0; i < NEMB; ++i) a += e[i] * Wih[r * NEMB + i];
        o[q] = a;
    }
    ((float4*)tbl)[tid] = make_float4(o[0], o[1], o[2], o[3]);
}

// ---------------------------------------------------------------------------
// Kernel 2: R5 geometry (16 lanes/batch, 4 batch/wave, 1024 waves, 4-deep
// compile-time-indexed table pipeline) with:
//  - h-broadcast via 15 DPP row_ror (D[l]=S[(l-r)&15], HW-verified R8),
//    results written straight into v2f pairs -> gate dot stays 32 pk_fma
//    with pair-packed permuted weights.
//  - two accumulators per gate (FMA dep chain halved).
//  - token indices register-prefetched one macro-iter ahead (R9): the idx
//    ds_read is off the table-load address path.
// No LDS in the recurrence; LDS only for idx staging.
// ---------------------------------------------------------------------------
__global__ __launch_bounds__(256) void lstm_dpk_kernel(
    const int*   __restrict__ x,
    const float* __restrict__ tbl,
    const float* __restrict__ Whh,
    const float* __restrict__ Wfc,
    const float* __restrict__ bfc,
    float*       __restrict__ out)
{
    __shared__ int idxs[16][IROW];   // [batch][t] token*16, 33.3 KB

    const int tid = threadIdx.x;
    const int j   = tid & 15;        // hidden unit owned
    const int lb  = tid >> 4;        // local batch 0..15
    const int batch = blockIdx.x * 16 + lb;

    // stage tokens, pre-scaled to float4-row index (v*16); tail -> 0
    #pragma unroll 1
    for (int b = 0; b < 16; ++b) {
        const int* xr = x + (size_t)(blockIdx.x * 16 + b) * T_LEN;
        for (int t = tid; t < IROW; t += 256)
            idxs[b][t] = (t < T_LEN) ? (xr[t] << 4) : 0;
    }
    __syncthreads();

    // pair-packed permuted weights: wp[q][s] = { w[q][2s], w[q][2s+1] },
    // w[q][r] = Whh[(q*16+j)][ (j-r)&15 ]
    v2f wp[4][8];
    #pragma unroll
    for (int q = 0; q < 4; ++q) {
        const int row = (q * 16 + j) * NHID;
        #pragma unroll
        for (int s = 0; s < 8; ++s)
            wp[q][s] = (v2f){Whh[row + ((j - 2 * s) & 15)],
                             Whh[row + ((j - 2 * s - 1) & 15)]};
    }

    float h = 0.f, c = 0.f;
    const float NL2E  = -1.44269504088896f;
    const float NL2E2 = -2.88539008177793f;
    const float4* t4 = (const float4*)tbl;

    // 4-deep table pipeline + register idx prefetch (one macro-iter ahead)
    float4 pf[4];
    int iv[4];
    #pragma unroll
    for (int s = 0; s < 4; ++s) {
        pf[s] = t4[idxs[lb][s] + j];
        iv[s] = idxs[lb][4 + s];
    }

    #pragma unroll 1
    for (int t = 0; t < T_LEN; t += 4) {
        // idx for NEXT macro-iter's refills (a full iteration of slack)
        int ivn[4];
        #pragma unroll
        for (int u = 0; u < 4; ++u) ivn[u] = idxs[lb][t + 8 + u];

        #pragma unroll
        for (int u = 0; u < 4; ++u) {
            const float4 tb = pf[u];
            pf[u] = t4[iv[u] + j];          // in flight 4 steps (counted vmcnt)

            // h-broadcast: hr[r] = h[(j-r)&15] via DPP row_ror, into pairs
            const int hvi = __builtin_bit_cast(int, h);
            #define ROR(r) __builtin_bit_cast(float, \
                __builtin_amdgcn_update_dpp(0, hvi, 0x120 + (r), 0xF, 0xF, true))
            v2f hrp[8];
            hrp[0] = (v2f){h,       ROR(1)};
            hrp[1] = (v2f){ROR(2),  ROR(3)};
            hrp[2] = (v2f){ROR(4),  ROR(5)};
            hrp[3] = (v2f){ROR(6),  ROR(7)};
            hrp[4] = (v2f){ROR(8),  ROR(9)};
            hrp[5] = (v2f){ROR(10), ROR(11)};
            hrp[6] = (v2f){ROR(12), ROR(13)};
            hrp[7] = (v2f){ROR(14), ROR(15)};
            #undef ROR

            // gates: two v2f accumulators each (halved dep chain), pk_fma
            v2f a0 = (v2f){tb.x, 0.f}, b0 = (v2f){0.f, 0.f};
            v2f a1 = (v2f){tb.y, 0.f}, b1 = (v2f){0.f, 0.f};
            v2f a2 = (v2f){tb.z, 0.f}, b2 = (v2f){0.f, 0.f};
            v2f a3 = (v2f){tb.w, 0.f}, b3 = (v2f){0.f, 0.f};
            #pragma unroll
            for (int s = 0; s < 4; ++s) {
                a0 += hrp[s] * wp[0][s];  b0 += hrp[s + 4] * wp[0][s + 4];
                a1 += hrp[s] * wp[1][s];  b1 += hrp[s + 4] * wp[1][s + 4];
                a2 += hrp[s] * wp[2][s];  b2 += hrp[s + 4] * wp[2][s + 4];
                a3 += hrp[s] * wp[3][s];  b3 += hrp[s + 4] * wp[3][s + 4];
            }
            const v2f s0 = a0 + b0, s1 = a1 + b1, s2 = a2 + b2, s3 = a3 + b3;
            const float v0 = s0.x + s0.y, v1 = s1.x + s1.y;
            const float v2 = s2.x + s2.y, v3 = s3.x + s3.y;

            const float ig = __builtin_amdgcn_rcpf(1.f + __builtin_amdgcn_exp2f(v0 * NL2E));
            const float fg = __builtin_amdgcn_rcpf(1.f + __builtin_amdgcn_exp2f(v1 * NL2E));
            const float gg = 2.f * __builtin_amdgcn_rcpf(1.f + __builtin_amdgcn_exp2f(v2 * NL2E2)) - 1.f;
            const float og = __builtin_amdgcn_rcpf(1.f + __builtin_amdgcn_exp2f(v3 * NL2E));

            c = fg * c + ig * gg;
            const float tc = 2.f * __builtin_amdgcn_rcpf(1.f + __builtin_amdgcn_exp2f(c * NL2E2)) - 1.f;
            h = og * tc;
        }

        #pragma unroll
        for (int u = 0; u < 4; ++u) iv[u] = ivn[u];
    }

    // logit: reduce h*Wfc over the 16-lane group (epilogue only)
    float s = h * Wfc[j];
    s += __shfl_xor(s, 1, 64);
    s += __shfl_xor(s, 2, 64);
    s += __shfl_xor(s, 4, 64);
    s += __shfl_xor(s, 8, 64);
    if (j == 0)
        out[batch] = __builtin_amdgcn_rcpf(1.f + __builtin_amdgcn_exp2f((s + bfc[0]) * NL2E));
}

// ---------------------------------------------------------------------------
// Fallback (ws too small for the 12.8 MB table): on-the-fly fp32 path.
// ---------------------------------------------------------------------------
__global__ __launch_bounds__(256) void lstm_fb_kernel(
    const int*   __restrict__ x,
    const float* __restrict__ emb,
    const float* __restrict__ Wih,
    const float* __restrict__ Whh,
    const float* __restrict__ bih,
    const float* __restrict__ bhh,
    const float* __restrict__ Wfc,
    const float* __restrict__ bfc,
    float*       __restrict__ out)
{
    __shared__ int   idx_lds[T_LEN][17];
    __shared__ float hx[16][20];

    const int tid  = threadIdx.x;
    const int lane = tid & 63;
    const int j    = lane & 15;
    const int lb   = tid >> 4;
    const int batch = blockIdx.x * 16 + lb;

    for (int i = tid; i < 16 * T_LEN; i += 256) {
        const int b = i & 15;
        const int t = i >> 4;
        idx_lds[t][b] = x[(blockIdx.x * 16 + b) * T_LEN + t];
    }

    float wih[4][NEMB], bias[4];
    v2f w[4][8];
    #pragma unroll
    for (int q = 0; q < 4; ++q) {
        const int r = j + 16 * q;
        #pragma unroll
        for (int e = 0; e < NEMB; ++e) wih[q][e] = Wih[r * NEMB + e];
        #pragma unroll
        for (int p = 0; p < 8; ++p)
            w[q][p] = (v2f){Whh[r * NHID + 2 * p], Whh[r * NHID + 2 * p + 1]};
        bias[q] = bih[r] + bhh[r];
    }

    __syncthreads();

    v2f h2[8];
    #pragma unroll
    for (int p = 0; p < 8; ++p) h2[p] = (v2f){0.f, 0.f};
    float c = 0.f;

    const float NL2E  = -1.44269504088896f;
    const float NL2E2 = -2.88539008177793f;
    const float4* hp = (const float4*)&hx[lb][0];

    float2 xa, xb, xc, xd, xe2;
    {
        const float2* er = (const float2*)(emb + (long)idx_lds[0][lb] * NEMB);
        xa = er[0]; xb = er[1]; xc = er[2]; xd = er[3]; xe2 = er[4];
    }
    int idx_n = idx_lds[1][lb];

    #pragma unroll 1
    for (int t = 0; t < T_LEN; ++t) {
        const float xv[NEMB] = {xa.x, xa.y, xb.x, xb.y, xc.x, xc.y,
                                xd.x, xd.y, xe2.x, xe2.y};
        if (t + 1 < T_LEN) {
            const float2* er = (const float2*)(emb + (long)idx_n * NEMB);
            xa = er[0]; xb = er[1]; xc = er[2]; xd = er[3]; xe2 = er[4];
        }
        const int idx_nn = (t + 2 < T_LEN) ? idx_lds[t + 2][lb] : 0;

        float v[4];
        #pragma unroll
        for (int q = 0; q < 4; ++q) {
            float a = bias[q];
            #pragma unroll
            for (int e = 0; e < NEMB; ++e) a += xv[e] * wih[q][e];
            v[q] = a;
        }
        v2f a0 = (v2f){v[0], 0.f}, a1 = (v2f){v[1], 0.f};
        v2f a2 = (v2f){v[2], 0.f}, a3 = (v2f){v[3], 0.f};
        #pragma unroll
        for (int p = 0; p < 8; ++p) {
            a0 += h2[p] * w[0][p];
            a1 += h2[p] * w[1][p];
            a2 += h2[p] * w[2][p];
            a3 += h2[p] * w[3][p];
        }
        const float vi = a0.x + a0.y, vf = a1.x + a1.y;
        const float vg = a2.x + a2.y, vo = a3.x + a3.y;

        const float ig = __builtin_amdgcn_rcpf(1.f + __builtin_amdgcn_exp2f(vi * NL2E));
        const float fg = __builtin_amdgcn_rcpf(1.f + __builtin_amdgcn_exp2f(vf * NL2E));
        const float gg = 2.f * __builtin_amdgcn_rcpf(1.f + __builtin_amdgcn_exp2f(vg * NL2E2)) - 1.f;
        const float og = __builtin_amdgcn_rcpf(1.f + __builtin_amdgcn_exp2f(vo * NL2E));

        c = fg * c + ig * gg;
        const float tc = 2.f * __builtin_amdgcn_rcpf(1.f + __builtin_amdgcn_exp2f(c * NL2E2)) - 1.f;
        const float hv = og * tc;

        hx[lb][j] = hv;
        const float4 b0 = hp[0], b1 = hp[1], b2 = hp[2], b3 = hp[3];
        h2[0] = (v2f){b0.x, b0.y}; h2[1] = (v2f){b0.z, b0.w};
        h2[2] = (v2f){b1.x, b1.y}; h2[3] = (v2f){b1.z, b1.w};
        h2[4] = (v2f){b2.x, b2.y}; h2[5] = (v2f){b2.z, b2.w};
        h2[6] = (v2f){b3.x, b3.y}; h2[7] = (v2f){b3.z, b3.w};

        idx_n = idx_nn;
    }

    if (j == 0) {
        float logit = bfc[0];
        #pragma unroll
        for (int p = 0; p < 8; ++p)
            logit += h2[p].x * Wfc[2 * p] + h2[p].y * Wfc[2 * p + 1];
        out[batch] = __builtin_amdgcn_rcpf(1.f + __builtin_amdgcn_exp2f(logit * NL2E));
    }
}

extern "C" void kernel_launch(void* const* d_in, const int* in_sizes, int n_in,
                              void* d_out, int out_size, void* d_ws, size_t ws_size,
                              hipStream_t stream) {
    const int*   x   = (const int*)  d_in[0];
    const float* emb = (const float*)d_in[1];
    const float* Wih = (const float*)d_in[2];
    const float* Whh = (const float*)d_in[3];
    const float* bih = (const float*)d_in[4];
    const float* bhh = (const float*)d_in[5];
    const float* Wfc = (const float*)d_in[6];
    const float* bfc = (const float*)d_in[7];
    float* outp = (float*)d_out;

    const int B = in_sizes[0] / T_LEN;                               // 4096
    const size_t TABLE_BYTES = (size_t)VOCAB1 * 64 * sizeof(float);  // 12.8 MB

    if (ws_size >= TABLE_BYTES) {
        float* tbl = (float*)d_ws;
        build_table<<<(VOCAB1 * 16 + 255) / 256, 256, 0, stream>>>(emb, Wih, bih, bhh, tbl);
        lstm_dpk_kernel<<<B / 16, 256, 0, stream>>>(x, tbl, Whh, Wfc, bfc, outp);
    } else {
        lstm_fb_kernel<<<B / 16, 256, 0, stream>>>(x, emb, Wih, Whh, bih, bhh, Wfc, bfc, outp);
    }
}